// Round 1
// baseline (810.554 us; speedup 1.0000x reference)
//
#include <hip/hip_runtime.h>

// VoxelUnshuffle strided: out[n, c*8 + i] = features[n*8 + i, c]
// N_VOXELS = 500000, VOLUME = 8, C = 32. Per voxel: transpose 8x32 -> 32x8,
// both input and output blocks are contiguous 256-float (1 KB) segments.
// Output 1 (indices) is passed through, written as float32 values since the
// harness reads the flat d_out as float32.

#define VPB 16               // voxels per block
#define FPV 256              // floats per voxel (VOLUME * C)

__global__ __launch_bounds__(256) void vox_unshuffle_kernel(
    const float* __restrict__ in, float* __restrict__ out, long long total_floats) {
    __shared__ float lds[VPB * FPV];  // 16 KB
    const int t = threadIdx.x;
    const long long base = (long long)blockIdx.x * (VPB * FPV);

    // ---- stage 1: coalesced global -> LDS, float4 ----
    const float4* in4 = (const float4*)(in + base);
    float4* lds4 = (float4*)lds;
#pragma unroll
    for (int k = 0; k < 4; ++k) {
        int p = t + 256 * k;
        if (base + 4LL * p < total_floats) {
            lds4[p] = in4[p];
        }
    }
    __syncthreads();

    // ---- stage 2: transposed LDS gather -> coalesced float4 store ----
    float4* out4 = (float4*)(out + base);
#pragma unroll
    for (int k = 0; k < 4; ++k) {
        int q = t + 256 * k;          // output float4 index within block chunk
        if (base + 4LL * q >= total_floats) continue;
        int n_local = q >> 6;         // which voxel (64 float4 per voxel)
        int c  = (q >> 1) & 31;       // channel
        int i0 = (q & 1) * 4;         // starting sub-voxel
        const float* src = lds + n_local * FPV + c;   // bank = c; 2 lanes/bank -> free
        float4 v;
        v.x = src[(i0 + 0) * 32];
        v.y = src[(i0 + 1) * 32];
        v.z = src[(i0 + 2) * 32];
        v.w = src[(i0 + 3) * 32];
        out4[q] = v;
    }
}

__global__ __launch_bounds__(256) void idx_to_float_kernel(
    const int* __restrict__ idx, float* __restrict__ out, int n_vec4) {
    int t = blockIdx.x * blockDim.x + threadIdx.x;
    if (t < n_vec4) {
        int4 v = ((const int4*)idx)[t];
        float4 f;
        f.x = (float)v.x; f.y = (float)v.y; f.z = (float)v.z; f.w = (float)v.w;
        ((float4*)out)[t] = f;
    }
}

extern "C" void kernel_launch(void* const* d_in, const int* in_sizes, int n_in,
                              void* d_out, int out_size, void* d_ws, size_t ws_size,
                              hipStream_t stream) {
    const float* features = (const float*)d_in[0];
    const int* indices    = (const int*)d_in[1];
    float* out            = (float*)d_out;

    const long long n_feat = in_sizes[0];       // 128,000,000 floats
    const int n_idx        = in_sizes[1];       // 2,000,000 int32
    const long long n_vox  = n_feat / FPV;      // 500,000

    // main transpose
    int blocks = (int)((n_vox + VPB - 1) / VPB);   // 31250
    vox_unshuffle_kernel<<<blocks, 256, 0, stream>>>(features, out, n_feat);

    // indices pass-through (as float32 values) at offset n_feat
    int n_vec4 = n_idx / 4;                        // 500,000 (divides exactly)
    int iblocks = (n_vec4 + 255) / 256;
    idx_to_float_kernel<<<iblocks, 256, 0, stream>>>(indices, out + n_feat, n_vec4);
}